// Round 6
// baseline (138.041 us; speedup 1.0000x reference)
//
#include <hip/hip_runtime.h>

#define NUM_LAYERS 32
#define HIDDEN 2048
#define RANK 64
#define BATCH 2048
#define CHK 256                // h-chunk size (K for phase1, N for phase2)
#define NCHK (HIDDEN / CHK)    // 8
#define SB 8                   // samples per block (M=16 tile, rows 8..15 inert)
#define NSC 16                 // sample-chunk slots; stride-loop covers n_l > 128
#define VPAD 264               // shorts/row, vt  (528 B = 33*16, stride 132 dw ≡ 4 mod 32)
#define ZPAD 264               // shorts/row, zt
#define UPAD 72                // shorts/row, ut  (144 B = 9*16, stride 36 dw ≡ 4 mod 32)
#define PPAD 72                // shorts/row, pt
#define PREPPAD 264            // shorts/row, prep transpose tile

typedef __attribute__((ext_vector_type(8))) short bf16x8;
typedef __attribute__((ext_vector_type(4))) float f32x4;

static __device__ __forceinline__ ushort f2bf(float x) {
    unsigned b = __builtin_bit_cast(unsigned, x);
    b += 0x7fffu + ((b >> 16) & 1u);          // round-to-nearest-even
    return (ushort)(b >> 16);
}
static __device__ __forceinline__ ushort4 pack4(float4 v) {
    ushort4 r; r.x = f2bf(v.x); r.y = f2bf(v.y); r.z = f2bf(v.z); r.w = f2bf(v.w);
    return r;
}

// Workspace: vbf[32][64][2048] bf16 (8 MB) | ubf[32][2048][64] bf16 (8 MB)
//            counts[32], offsets[32], perm[2048]

// K1: blocks 0..255: V convert+transpose; 256..511: U convert; 512: bucket sort
__global__ __launch_bounds__(256)
void k_prep(const float* __restrict__ v, const float* __restrict__ u,
            const int* __restrict__ ids,
            ushort* __restrict__ vbf, ushort* __restrict__ ubf,
            int* __restrict__ counts, int* __restrict__ offsets,
            int* __restrict__ perm)
{
    const int b = blockIdx.x, t = threadIdx.x;
    if (b < 256) {
        const int l = b >> 3, kbase = (b & 7) * CHK;
        __shared__ ushort vtile[RANK * PREPPAD];   // ~34 KB
        #pragma unroll
        for (int it = 0; it < 16; ++it) {
            const int idx = it * 256 + t;              // 4096 float4
            const int hh = idx >> 4, rq = idx & 15;    // coalesced reads
            const float4 f = *(const float4*)
                &v[((size_t)l * HIDDEN + kbase + hh) * RANK + rq * 4];
            vtile[(rq * 4 + 0) * PREPPAD + hh] = f2bf(f.x);
            vtile[(rq * 4 + 1) * PREPPAD + hh] = f2bf(f.y);
            vtile[(rq * 4 + 2) * PREPPAD + hh] = f2bf(f.z);
            vtile[(rq * 4 + 3) * PREPPAD + hh] = f2bf(f.w);
        }
        __syncthreads();
        #pragma unroll
        for (int it = 0; it < 8; ++it) {
            const int idx = it * 256 + t;              // 2048 b128 units
            const int r = idx >> 5, c = idx & 31;
            const bf16x8 d = *(const bf16x8*)&vtile[r * PREPPAD + c * 8];
            *(bf16x8*)&vbf[((size_t)l * RANK + r) * HIDDEN + kbase + c * 8] = d;
        }
    } else if (b < 512) {
        const int bb = b - 256;
        const int l = bb >> 3, hbase = (bb & 7) * CHK;
        #pragma unroll
        for (int it = 0; it < 16; ++it) {
            const int idx = it * 256 + t;
            const int hh = idx >> 4, rq = idx & 15;
            const size_t off = ((size_t)l * HIDDEN + hbase + hh) * RANK + rq * 4;
            const float4 f = *(const float4*)&u[off];
            *(ushort4*)&ubf[off] = pack4(f);           // coalesced 8B stores
        }
    } else {
        __shared__ int cnt[NUM_LAYERS];
        __shared__ int off[NUM_LAYERS];
        __shared__ int cur[NUM_LAYERS];
        if (t < NUM_LAYERS) cnt[t] = 0;
        __syncthreads();
        for (int i = t; i < BATCH; i += 256) atomicAdd(&cnt[ids[i]], 1);
        __syncthreads();
        if (t == 0) {
            int a = 0;
            for (int l = 0; l < NUM_LAYERS; ++l) { off[l] = a; a += cnt[l]; }
        }
        __syncthreads();
        if (t < NUM_LAYERS) { cur[t] = 0; counts[t] = cnt[t]; offsets[t] = off[t]; }
        __syncthreads();
        for (int i = t; i < BATCH; i += 256) {
            int l = ids[i];
            int p = off[l] + atomicAdd(&cur[l], 1);
            perm[p] = i;
        }
    }
}

// K2: fused per-(layer, sample-chunk) block.
// Phase 1: P = Z·V over 8 k-chunks (MFMA 16x16x32 bf16, wave w owns r-tile w).
// P -> LDS (bf16, A-layout), Phase 2: delta = P·U^T over 8 h-chunks, out = z+delta.
// M-tile rows 8..15 are pad: MFMA rows are independent, so garbage there is inert.
__global__ __launch_bounds__(256)
void k_fused(const float* __restrict__ z,
             const ushort* __restrict__ vbf, const ushort* __restrict__ ubf,
             const int* __restrict__ counts, const int* __restrict__ offsets,
             const int* __restrict__ perm, float* __restrict__ out)
{
    const int sc = blockIdx.x, l = blockIdx.y;
    const int n = counts[l], o = offsets[l];
    const int t = threadIdx.x;
    const int w = t >> 6, lane = t & 63;
    const int m16 = lane & 15, quad = lane >> 4;

    __shared__ ushort smem[RANK * VPAD + 16 * ZPAD];  // 21120 shorts (42.2 KB)
    __shared__ ushort pt[16 * PPAD];                  // 2.3 KB
    __shared__ int bidx[SB];
    ushort* vt = smem;                 // phase1: [r][h]
    ushort* zt = smem + RANK * VPAD;   // phase1: [si][h]
    ushort* ut = smem;                 // phase2: [h][r] (18432 <= 21120, reuse)

    for (int base = sc * SB; base < n; base += NSC * SB) {
        const int nb = (n - base < SB) ? (n - base) : SB;
        __syncthreads();                         // smem/bidx reuse guard
        if (t < SB) bidx[t] = (t < nb) ? perm[o + base + t] : 0;

        // ---- phase 1: P[si][r] = sum_h Z[si][h] * V[h][r] ----
        f32x4 acc = {0.f, 0.f, 0.f, 0.f};
        for (int kc = 0; kc < NCHK; ++kc) {
            const int kbase = kc * CHK;
            __syncthreads();                     // prior MFMA reads done
            #pragma unroll
            for (int it = 0; it < 8; ++it) {     // vt: pure b128 copy, 32 KB
                const int idx = it * 256 + t;
                const int r = idx >> 5, c = idx & 31;
                const bf16x8 d = *(const bf16x8*)
                    &vbf[((size_t)l * RANK + r) * HIDDEN + kbase + c * 8];
                *(bf16x8*)&vt[r * VPAD + c * 8] = d;
            }
            #pragma unroll
            for (int it = 0; it < 2; ++it) {     // zt: 8 rows fp32->bf16
                const int idx = it * 256 + t;
                const int si = idx >> 6, q = idx & 63;
                if (si < nb) {
                    const float4 f = *(const float4*)
                        &z[(size_t)bidx[si] * HIDDEN + kbase + q * 4];
                    *(ushort4*)&zt[si * ZPAD + q * 4] = pack4(f);
                }
            }
            __syncthreads();
            #pragma unroll
            for (int kt = 0; kt < 8; ++kt) {
                const int koff = kt * 32 + quad * 8;
                const bf16x8 a  = *(const bf16x8*)&zt[m16 * ZPAD + koff];
                const bf16x8 bm = *(const bf16x8*)&vt[(w * 16 + m16) * VPAD + koff];
                acc = __builtin_amdgcn_mfma_f32_16x16x32_bf16(a, bm, acc, 0, 0, 0);
            }
        }
        // C/D: col(r in wave tile)=lane&15, row(si)=quad*4+reg  ->  pt[si][r] bf16
        #pragma unroll
        for (int reg = 0; reg < 4; ++reg)
            pt[(quad * 4 + reg) * PPAD + w * 16 + m16] = f2bf(acc[reg]);
        __syncthreads();                         // pt ready; all vt reads done

        // A-fragments of P (K=64): A[m=lane&15][k=quad*8+j]
        const bf16x8 pa0 = *(const bf16x8*)&pt[m16 * PPAD + quad * 8];
        const bf16x8 pa1 = *(const bf16x8*)&pt[m16 * PPAD + 32 + quad * 8];

        // ---- phase 2: out[si][h] = z + sum_r P[si][r] * U[h][r] ----
        for (int hc = 0; hc < NCHK; ++hc) {
            const int hbase = hc * CHK;
            if (hc) __syncthreads();             // prior ut reads done
            #pragma unroll
            for (int it = 0; it < 8; ++it) {     // ut: pure b128 copy, 32 KB
                const int idx = it * 256 + t;
                const int hh = idx >> 3, rq = idx & 7;
                const bf16x8 d = *(const bf16x8*)
                    &ubf[((size_t)l * HIDDEN + hbase + hh) * RANK + rq * 8];
                *(bf16x8*)&ut[hh * UPAD + rq * 8] = d;
            }
            __syncthreads();

            f32x4 acc2[4];
            #pragma unroll
            for (int nt = 0; nt < 4; ++nt) acc2[nt] = (f32x4){0.f, 0.f, 0.f, 0.f};
            #pragma unroll
            for (int nt = 0; nt < 4; ++nt) {
                const int hcol = (w * 4 + nt) * 16 + m16;
                const bf16x8 b0 = *(const bf16x8*)&ut[hcol * UPAD + quad * 8];
                const bf16x8 b1 = *(const bf16x8*)&ut[hcol * UPAD + 32 + quad * 8];
                acc2[nt] = __builtin_amdgcn_mfma_f32_16x16x32_bf16(pa0, b0, acc2[nt], 0, 0, 0);
                acc2[nt] = __builtin_amdgcn_mfma_f32_16x16x32_bf16(pa1, b1, acc2[nt], 0, 0, 0);
            }
            // epilogue: rows si=quad*4+reg (si<nb), cols w*64 + nt*16 + m16
            #pragma unroll
            for (int reg = 0; reg < 4; ++reg) {
                const int si = quad * 4 + reg;
                if (si < nb) {
                    const size_t rowb = (size_t)bidx[si] * HIDDEN + hbase;
                    #pragma unroll
                    for (int nt = 0; nt < 4; ++nt) {
                        const int hcol = (w * 4 + nt) * 16 + m16;
                        out[rowb + hcol] = z[rowb + hcol] + acc2[nt][reg];
                    }
                }
            }
        }
    }
}

extern "C" void kernel_launch(void* const* d_in, const int* in_sizes, int n_in,
                              void* d_out, int out_size, void* d_ws, size_t ws_size,
                              hipStream_t stream)
{
    const float* z   = (const float*)d_in[0];
    const int*   ids = (const int*)d_in[1];
    const float* u   = (const float*)d_in[2];
    const float* v   = (const float*)d_in[3];
    float* out = (float*)d_out;

    ushort* vbf  = (ushort*)d_ws;                                  // 8 MB
    ushort* ubf  = vbf + (size_t)NUM_LAYERS * RANK * HIDDEN;       // 8 MB
    int* counts  = (int*)(ubf + (size_t)NUM_LAYERS * HIDDEN * RANK);
    int* offsets = counts + NUM_LAYERS;
    int* perm    = offsets + NUM_LAYERS;

    hipLaunchKernelGGL(k_prep, dim3(513), dim3(256), 0, stream,
                       v, u, ids, vbf, ubf, counts, offsets, perm);
    hipLaunchKernelGGL(k_fused, dim3(NSC, NUM_LAYERS), dim3(256), 0, stream,
                       z, vbf, ubf, counts, offsets, perm, out);
}

// Round 7
// 114.873 us; speedup vs baseline: 1.2017x; 1.2017x over previous
//
#include <hip/hip_runtime.h>

#define NUM_LAYERS 32
#define HIDDEN 2048
#define RANK 64
#define BATCH 2048
#define CHK 256                // h-chunk (K for phase1, N for phase2)
#define SCP 4                  // sample-chunk grid split, both phases
#define MB 16                  // samples per block pass (one M=16 tile)
#define ZPAD 264               // shorts/row zt (528 B = 33*16)
#define PPAD 72                // shorts/row pt (144 B = 9*16)
#define PREPPAD 264

typedef __attribute__((ext_vector_type(8))) short bf16x8;
typedef __attribute__((ext_vector_type(4))) float f32x4;

static __device__ __forceinline__ ushort f2bf(float x) {
    unsigned b = __builtin_bit_cast(unsigned, x);
    b += 0x7fffu + ((b >> 16) & 1u);          // round-to-nearest-even
    return (ushort)(b >> 16);
}
static __device__ __forceinline__ ushort4 pack4(float4 v) {
    ushort4 r; r.x = f2bf(v.x); r.y = f2bf(v.y); r.z = f2bf(v.z); r.w = f2bf(v.w);
    return r;
}

// Workspace: vbf[32][64][2048] bf16 (8 MB, V transposed) | ubf[32][2048][64] bf16
//            | proj[2048][64] f32 | counts[32] offsets[32] perm[2048]

// blocks 0..255: V convert+transpose; 256..511: U convert; 512..575: zero proj;
// 576: bucket sort.
__global__ __launch_bounds__(256)
void k_prep(const float* __restrict__ v, const float* __restrict__ u,
            const int* __restrict__ ids,
            ushort* __restrict__ vbf, ushort* __restrict__ ubf,
            float* __restrict__ proj,
            int* __restrict__ counts, int* __restrict__ offsets,
            int* __restrict__ perm)
{
    const int b = blockIdx.x, t = threadIdx.x;
    if (b < 256) {
        const int l = b >> 3, kbase = (b & 7) * CHK;
        __shared__ ushort vtile[RANK * PREPPAD];
        #pragma unroll
        for (int it = 0; it < 16; ++it) {
            const int idx = it * 256 + t;              // 4096 float4, coalesced
            const int hh = idx >> 4, rq = idx & 15;
            const float4 f = *(const float4*)
                &v[((size_t)l * HIDDEN + kbase + hh) * RANK + rq * 4];
            vtile[(rq * 4 + 0) * PREPPAD + hh] = f2bf(f.x);
            vtile[(rq * 4 + 1) * PREPPAD + hh] = f2bf(f.y);
            vtile[(rq * 4 + 2) * PREPPAD + hh] = f2bf(f.z);
            vtile[(rq * 4 + 3) * PREPPAD + hh] = f2bf(f.w);
        }
        __syncthreads();
        #pragma unroll
        for (int it = 0; it < 8; ++it) {
            const int idx = it * 256 + t;              // 2048 b128 stores
            const int r = idx >> 5, c = idx & 31;
            const bf16x8 d = *(const bf16x8*)&vtile[r * PREPPAD + c * 8];
            *(bf16x8*)&vbf[((size_t)l * RANK + r) * HIDDEN + kbase + c * 8] = d;
        }
    } else if (b < 512) {
        const int bb = b - 256;
        const int l = bb >> 3, hbase = (bb & 7) * CHK;
        #pragma unroll
        for (int it = 0; it < 16; ++it) {
            const int idx = it * 256 + t;
            const int hh = idx >> 4, rq = idx & 15;
            const size_t off = ((size_t)l * HIDDEN + hbase + hh) * RANK + rq * 4;
            const float4 f = *(const float4*)&u[off];
            *(ushort4*)&ubf[off] = pack4(f);
        }
    } else if (b < 576) {
        const int base = (b - 512) * (BATCH * RANK / 64);
        for (int i = t; i < BATCH * RANK / 64; i += 256) proj[base + i] = 0.0f;
    } else {
        __shared__ int cnt[NUM_LAYERS];
        __shared__ int off[NUM_LAYERS];
        __shared__ int cur[NUM_LAYERS];
        if (t < NUM_LAYERS) cnt[t] = 0;
        __syncthreads();
        for (int i = t; i < BATCH; i += 256) atomicAdd(&cnt[ids[i]], 1);
        __syncthreads();
        if (t == 0) {
            int a = 0;
            for (int l = 0; l < NUM_LAYERS; ++l) { off[l] = a; a += cnt[l]; }
        }
        __syncthreads();
        if (t < NUM_LAYERS) { cur[t] = 0; counts[t] = cnt[t]; offsets[t] = off[t]; }
        __syncthreads();
        for (int i = t; i < BATCH; i += 256) {
            int l = ids[i];
            int p = off[l] + atomicAdd(&cur[l], 1);
            perm[p] = i;
        }
    }
}

// K2: proj[b,r] += sum_{h in kc} z[b,h] * v[l,h,r]
// grid (8 kc, 32 l, 4 sc) x 256. LDS: zt only. B-fragments read directly
// from global vbf (L2/L3-resident, 16B aligned per lane).
__global__ __launch_bounds__(256)
void k_proj(const float* __restrict__ z, const ushort* __restrict__ vbf,
            const int* __restrict__ counts, const int* __restrict__ offsets,
            const int* __restrict__ perm, float* __restrict__ proj)
{
    const int kc = blockIdx.x, l = blockIdx.y, sc = blockIdx.z;
    const int n = counts[l], o = offsets[l];
    if (sc * MB >= n) return;
    const int t = threadIdx.x;
    const int w = t >> 6, lane = t & 63;
    const int m16 = lane & 15, quad = lane >> 4;
    const int kbase = kc * CHK;

    __shared__ ushort zt[MB * ZPAD];   // 8.4 KB
    __shared__ int bidx[MB];

    // per-lane B pointer: row r = w*16+m16 of vbf[l], k-offset quad*8
    const ushort* vb = vbf + ((size_t)l * RANK + w * 16 + m16) * HIDDEN
                     + kbase + quad * 8;

    for (int base = sc * MB; base < n; base += SCP * MB) {
        const int nb = (n - base < MB) ? (n - base) : MB;
        __syncthreads();                       // zt/bidx reuse guard
        if (t < MB) bidx[t] = (t < nb) ? perm[o + base + t] : 0;
        __syncthreads();
        // stage 16 z rows (fp32 -> bf16), 1024 float4: 4 per thread
        #pragma unroll
        for (int it = 0; it < 4; ++it) {
            const int idx = it * 256 + t;
            const int si = idx >> 6, q = idx & 63;
            const float4 f = *(const float4*)
                &z[(size_t)bidx[si] * HIDDEN + kbase + q * 4];  // pad rows read row 0
            *(ushort4*)&zt[si * ZPAD + q * 4] = pack4(f);
        }
        __syncthreads();

        f32x4 acc = {0.f, 0.f, 0.f, 0.f};
        #pragma unroll
        for (int kt = 0; kt < 8; ++kt) {
            const bf16x8 a = *(const bf16x8*)&zt[m16 * ZPAD + kt * 32 + quad * 8];
            const bf16x8 bm = *(const bf16x8*)&vb[kt * 32];     // global b128
            acc = __builtin_amdgcn_mfma_f32_16x16x32_bf16(a, bm, acc, 0, 0, 0);
        }
        // C/D: col=r-within-tile=m16, row=si=quad*4+reg
        #pragma unroll
        for (int reg = 0; reg < 4; ++reg) {
            const int row = quad * 4 + reg;
            if (row < nb)
                atomicAdd(&proj[(size_t)bidx[row] * RANK + w * 16 + m16], acc[reg]);
        }
    }
}

// K3: out[b,h] = z[b,h] + sum_r proj[b,r] * u[l,h,r]
// grid (8 hc, 32 l, 4 sc) x 256. LDS: pt only (2.3 KB). B-fragments direct
// from global ubf.
__global__ __launch_bounds__(256)
void k_delta(const float* __restrict__ z, const ushort* __restrict__ ubf,
             const int* __restrict__ counts, const int* __restrict__ offsets,
             const int* __restrict__ perm, const float* __restrict__ proj,
             float* __restrict__ out)
{
    const int hc = blockIdx.x, l = blockIdx.y, sc = blockIdx.z;
    const int n = counts[l], o = offsets[l];
    if (sc * MB >= n) return;
    const int t = threadIdx.x;
    const int w = t >> 6, lane = t & 63;
    const int m16 = lane & 15, quad = lane >> 4;
    const int hbase = hc * CHK;

    __shared__ ushort pt[MB * PPAD];   // 2.3 KB
    __shared__ int bidx[MB];

    const ushort* ub = ubf + ((size_t)l * HIDDEN + hbase) * RANK;

    for (int base = sc * MB; base < n; base += SCP * MB) {
        const int nb = (n - base < MB) ? (n - base) : MB;
        __syncthreads();
        if (t < MB) bidx[t] = (t < nb) ? perm[o + base + t] : 0;
        __syncthreads();
        // stage proj rows (fp32 -> bf16): 256 float4, 1 per thread
        {
            const int si = t >> 4, rq = t & 15;
            const float4 f = *(const float4*)&proj[(size_t)bidx[si] * RANK + rq * 4];
            *(ushort4*)&pt[si * PPAD + rq * 4] = pack4(f);
        }
        __syncthreads();

        // A-fragments of P (K=64)
        const bf16x8 pa0 = *(const bf16x8*)&pt[m16 * PPAD + quad * 8];
        const bf16x8 pa1 = *(const bf16x8*)&pt[m16 * PPAD + 32 + quad * 8];

        f32x4 acc[4];
        #pragma unroll
        for (int nt = 0; nt < 4; ++nt) acc[nt] = (f32x4){0.f, 0.f, 0.f, 0.f};
        #pragma unroll
        for (int nt = 0; nt < 4; ++nt) {
            const int hcol = (w * 4 + nt) * 16 + m16;
            const bf16x8 b0 = *(const bf16x8*)&ub[hcol * RANK + quad * 8];
            const bf16x8 b1 = *(const bf16x8*)&ub[hcol * RANK + 32 + quad * 8];
            acc[nt] = __builtin_amdgcn_mfma_f32_16x16x32_bf16(pa0, b0, acc[nt], 0, 0, 0);
            acc[nt] = __builtin_amdgcn_mfma_f32_16x16x32_bf16(pa1, b1, acc[nt], 0, 0, 0);
        }
        // epilogue: rows si=quad*4+reg, cols w*64 + nt*16 + m16
        #pragma unroll
        for (int reg = 0; reg < 4; ++reg) {
            const int si = quad * 4 + reg;
            if (si < nb) {
                const size_t rowb = (size_t)bidx[si] * HIDDEN + hbase;
                #pragma unroll
                for (int nt = 0; nt < 4; ++nt) {
                    const int hcol = (w * 4 + nt) * 16 + m16;
                    out[rowb + hcol] = z[rowb + hcol] + acc[nt][reg];
                }
            }
        }
    }
}

extern "C" void kernel_launch(void* const* d_in, const int* in_sizes, int n_in,
                              void* d_out, int out_size, void* d_ws, size_t ws_size,
                              hipStream_t stream)
{
    const float* z   = (const float*)d_in[0];
    const int*   ids = (const int*)d_in[1];
    const float* u   = (const float*)d_in[2];
    const float* v   = (const float*)d_in[3];
    float* out = (float*)d_out;

    ushort* vbf  = (ushort*)d_ws;                                  // 8 MB
    ushort* ubf  = vbf + (size_t)NUM_LAYERS * RANK * HIDDEN;       // 8 MB
    float*  proj = (float*)(ubf + (size_t)NUM_LAYERS * HIDDEN * RANK); // 512 KB
    int* counts  = (int*)(proj + (size_t)BATCH * RANK);
    int* offsets = counts + NUM_LAYERS;
    int* perm    = offsets + NUM_LAYERS;

    hipLaunchKernelGGL(k_prep, dim3(577), dim3(256), 0, stream,
                       v, u, ids, vbf, ubf, proj, counts, offsets, perm);
    hipLaunchKernelGGL(k_proj, dim3(HIDDEN / CHK, NUM_LAYERS, SCP), dim3(256), 0, stream,
                       z, vbf, counts, offsets, perm, proj);
    hipLaunchKernelGGL(k_delta, dim3(HIDDEN / CHK, NUM_LAYERS, SCP), dim3(256), 0, stream,
                       z, ubf, counts, offsets, perm, proj, out);
}